// Round 5
// baseline (381.478 us; speedup 1.0000x reference)
//
#include <hip/hip_runtime.h>
#include <hip/hip_bf16.h>
#include <math.h>

#define NPTS   4096
#define NB     4
#define NC     61
#define NIN    64
#define NOUT   128
#define NK     16
#define NROWS  16384           // NB*NPTS
#define BN_EPS 1e-5f
#define INV_ROWS (1.0f/16384.0f)

// ---------------------------------------------------------------------------
// Kernel 0: pack pos (Nx3) into float4 (Nx4) for single-load candidates.
// ---------------------------------------------------------------------------
__global__ __launch_bounds__(256) void prep_pos4(const float* __restrict__ pos,
                                                 float4* __restrict__ pos4) {
    const int i = blockIdx.x * 256 + threadIdx.x;
    if (i < NB * NPTS)
        pos4[i] = make_float4(pos[i * 3 + 0], pos[i * 3 + 1], pos[i * 3 + 2], 0.f);
}

// ---------------------------------------------------------------------------
// Kernel 1: exact KNN (top-16 smallest d2, tie-break by smaller index).
// 2048 blocks x 256 threads; 8 queries/block, 32 lanes/query (lane L scans
// j % 32 == L, 128 candidates each). Packed u64 keys (d2_bits<<32 | idx).
//  - QUERY-SHARED threshold: after each compaction, thr = min over the
//    query's 32 lanes of each lane's 16th-best (valid prune: union 16th <=
//    every lane 16th). Survivors/query ~120 instead of ~960.
//  - ring OCAP=8 per thread in LDS (16.5 KB -> 8 blocks/CU, 32 waves/CU).
//  - final: cross-lane bitonic register merge (5 rounds); both partners of
//    each round compute the identical union-low-16, so all 32 lanes converge
//    to the query's sorted top-16 with no LDS traffic and no barriers.
// ---------------------------------------------------------------------------
#define OCAP 8
#define NPAD 257               // column stride (u64 entries)

__global__ __launch_bounds__(256) void knn_kernel(const float4* __restrict__ pos4,
                                                  int* __restrict__ idx_out) {
    __shared__ unsigned long long buf[OCAP * NPAD];   // 16.5 KB
    const int t  = threadIdx.x;
    const int b  = blockIdx.x >> 9;            // 512 blocks per batch
    const int q0 = (blockIdx.x & 511) * 8;
    const float4* __restrict__ pb = pos4 + b * NPTS;

    const int qloc = t >> 5;
    const int l32  = t & 31;
    const int qi   = q0 + qloc;

    const float4 qp = pb[qi];
    const float qx = qp.x, qy = qp.y, qz = qp.z;

    unsigned long long bk[16];
#pragma unroll
    for (int i = 0; i < 16; ++i) bk[i] = ~0ull;
    unsigned int thr_bits = 0xFFFFFFFFu;
    int owptr = 0;

    auto compact = [&]() {
        unsigned long long od[OCAP];
#pragma unroll
        for (int s = 0; s < OCAP; ++s) {
            const unsigned long long v = buf[s * NPAD + t];
            od[s] = (s < owptr) ? v : ~0ull;
        }
        owptr = 0;
        // bitonic sort od[8] ascending
#pragma unroll
        for (int k = 2; k <= 8; k <<= 1) {
#pragma unroll
            for (int j = k >> 1; j > 0; j >>= 1) {
#pragma unroll
                for (int i = 0; i < 8; ++i) {
                    const int l = i ^ j;
                    if (l > i) {
                        const bool up = ((i & k) == 0);
                        const unsigned long long a = od[i], c = od[l];
                        const bool sw = up ? (c < a) : (a < c);
                        od[i] = sw ? c : a;
                        od[l] = sw ? a : c;
                    }
                }
            }
        }
        // merge: bk(16,asc) + od(8,asc): low-16 of bitonic-24 via min(bk[i], od[15-i])
#pragma unroll
        for (int i = 8; i < 16; ++i) {
            const unsigned long long c = od[15 - i];
            bk[i] = (c < bk[i]) ? c : bk[i];
        }
        // bk is bitonic -> cleanup sort ascending
#pragma unroll
        for (int j = 8; j > 0; j >>= 1) {
#pragma unroll
            for (int i = 0; i < 16; ++i) {
                const int l = i ^ j;
                if (l > i) {
                    const unsigned long long a = bk[i], c = bk[l];
                    const bool sw = (c < a);
                    bk[i] = sw ? c : a;
                    bk[l] = sw ? a : c;
                }
            }
        }
        // query-shared threshold: min of 16th-best across the 32 lanes
        unsigned int th = (unsigned int)(bk[15] >> 32);
#pragma unroll
        for (int m = 1; m <= 16; m <<= 1) {
            const unsigned int o = __shfl_xor(th, m, 32);
            th = (o < th) ? o : th;
        }
        thr_bits = th;
    };

    // scan: 128 candidates per lane; append survivors, compact check per 4
    for (int g = 0; g < 32; ++g) {
#pragma unroll
        for (int u = 0; u < 4; ++u) {
            const int j = (((g << 2) | u) << 5) | l32;
            const float4 p = pb[j];
            const float dx = qx - p.x, dy = qy - p.y, dz = qz - p.z;
            // match numpy fp32 exactly: squares + sequential adds, no contraction
            const float d2 = __fadd_rn(__fadd_rn(__fmul_rn(dx, dx), __fmul_rn(dy, dy)),
                                       __fmul_rn(dz, dz));
            if (__float_as_uint(d2) < thr_bits) {
                buf[owptr * NPAD + t] =
                    ((unsigned long long)__float_as_uint(d2) << 32) | (unsigned int)j;
                owptr++;
            }
        }
        if (__any(owptr > OCAP - 4)) compact();
    }
    compact();   // bk = lane's exact sorted top-16 of its slice

    // cross-lane bitonic merge: 5 rounds; after each, both partners hold the
    // identical sorted union-low-16 -> all 32 lanes converge to query top-16.
#pragma unroll
    for (int m = 1; m <= 16; m <<= 1) {
        unsigned long long ot[16];
#pragma unroll
        for (int i = 0; i < 16; ++i) ot[i] = __shfl_xor(bk[i], m, 32);
#pragma unroll
        for (int i = 0; i < 16; ++i) {
            const unsigned long long c = ot[15 - i];
            bk[i] = (c < bk[i]) ? c : bk[i];
        }
#pragma unroll
        for (int j = 8; j > 0; j >>= 1) {
#pragma unroll
            for (int i = 0; i < 16; ++i) {
                const int l = i ^ j;
                if (l > i) {
                    const unsigned long long a = bk[i], c = bk[l];
                    const bool sw = (c < a);
                    bk[i] = sw ? c : a;
                    bk[l] = sw ? a : c;
                }
            }
        }
    }

    if (l32 == 0) {
        const int ob = ((b << 12) | qi) * NK;
        int4 r0 = make_int4((int)bk[0],  (int)bk[1],  (int)bk[2],  (int)bk[3]);
        int4 r1 = make_int4((int)bk[4],  (int)bk[5],  (int)bk[6],  (int)bk[7]);
        int4 r2 = make_int4((int)bk[8],  (int)bk[9],  (int)bk[10], (int)bk[11]);
        int4 r3 = make_int4((int)bk[12], (int)bk[13], (int)bk[14], (int)bk[15]);
        *(int4*)&idx_out[ob + 0]  = r0;
        *(int4*)&idx_out[ob + 4]  = r1;
        *(int4*)&idx_out[ob + 8]  = r2;
        *(int4*)&idx_out[ob + 12] = r3;
    }
}

// ---------------------------------------------------------------------------
// Kernel 2: relation MLP (10->32->64->64) + weighted max-pool over K.
// 2 items per thread (k and k+8 of the same query). Layer-2/3 weights stored
// in LDS as bf16 pairs packed in dwords: halves the ds_read_b128 count (the
// LDS pipe was the bottleneck); unpack = 1 VALU op per weight.
// ---------------------------------------------------------------------------
__device__ __forceinline__ unsigned int f2bf(float f) {   // RNE to bf16 bits
    unsigned int b = __float_as_uint(f);
    return (b + 0x7FFFu + ((b >> 16) & 1u)) >> 16;
}
#define BFLO(u) __uint_as_float((u) << 16)
#define BFHI(u) __uint_as_float((u) & 0xFFFF0000u)

__global__ __launch_bounds__(256) void mlp_kernel(
    const float4* __restrict__ pos4, const float* __restrict__ x,
    const int* __restrict__ idx,
    const float* __restrict__ rw1, const float* __restrict__ rb1,
    const float* __restrict__ rw2, const float* __restrict__ rb2,
    const float* __restrict__ rw3, const float* __restrict__ rb3,
    float* __restrict__ pooled) {
    __shared__ float w1s[320], b1s[32], b2s[64], b3s[64];
    __shared__ unsigned int w2p[1024];   // [i][opair]: w2[i][2q] | w2[i][2q+1]<<16
    __shared__ unsigned int w3p[2048];   // [o][ipair]: w3[2q][o] | w3[2q+1][o]<<16
    const int t = threadIdx.x;
    for (int i = t; i < 320; i += 256)  w1s[i] = rw1[i];
    for (int i = t; i < 1024; i += 256) {
        const int row = i >> 5, q = i & 31;
        w2p[i] = f2bf(rw2[row * 64 + 2 * q]) | (f2bf(rw2[row * 64 + 2 * q + 1]) << 16);
    }
    for (int i = t; i < 2048; i += 256) {
        const int o = i >> 5, q = i & 31;
        w3p[i] = f2bf(rw3[(2 * q) * 64 + o]) | (f2bf(rw3[(2 * q + 1) * 64 + o]) << 16);
    }
    if (t < 32)                 b1s[t] = rb1[t];
    else if (t >= 32 && t < 96) b2s[t - 32] = rb2[t - 32];
    else if (t >= 96 && t < 160) b3s[t - 96] = rb3[t - 96];
    __syncthreads();

    const int k8   = t & 7;
    const int qloc = t >> 3;                   // 32 queries per block
    const int q    = blockIdx.x * 32 + qloc;   // 0..16383
    const int b    = q >> 12, n = q & 4095;
    const int j0 = idx[(size_t)q * NK + k8];
    const int j1 = idx[(size_t)q * NK + k8 + 8];
    const float4* __restrict__ pb = pos4 + b * NPTS;

    const float4 cp = pb[n];
    const float4 pa = pb[j0];
    const float4 pc = pb[j1];
    const float rxa = pa.x - cp.x, rya = pa.y - cp.y, rza = pa.z - cp.z;
    const float rxb = pc.x - cp.x, ryb = pc.y - cp.y, rzb = pc.z - cp.z;
    const float ssa = rxa * rxa + rya * rya + rza * rza;
    const float ssb = rxb * rxb + ryb * ryb + rzb * rzb;
    const float disa = (ssa > 0.f) ? sqrtf(ssa) : 0.f;
    const float disb = (ssb > 0.f) ? sqrtf(ssb) : 0.f;
    const float rina[10] = {cp.x, cp.y, cp.z, pa.x, pa.y, pa.z, rxa, rya, rza, disa};
    const float rinb[10] = {cp.x, cp.y, cp.z, pc.x, pc.y, pc.z, rxb, ryb, rzb, disb};

    float h1a[32], h1b[32];
#pragma unroll
    for (int o = 0; o < 32; ++o) { h1a[o] = b1s[o]; h1b[o] = h1a[o]; }
#pragma unroll
    for (int i = 0; i < 10; ++i) {
        const float va = rina[i], vb = rinb[i];
#pragma unroll
        for (int o = 0; o < 32; ++o) {
            const float w = w1s[i * 32 + o];
            h1a[o] += va * w; h1b[o] += vb * w;
        }
    }
#pragma unroll
    for (int o = 0; o < 32; ++o) { h1a[o] = fmaxf(h1a[o], 0.f); h1b[o] = fmaxf(h1b[o], 0.f); }

    float h2a[64], h2b[64];
#pragma unroll
    for (int o = 0; o < 64; ++o) { h2a[o] = b2s[o]; h2b[o] = h2a[o]; }
    for (int i = 0; i < 32; ++i) {
        const float va = h1a[i], vb = h1b[i];
#pragma unroll
        for (int op = 0; op < 8; ++op) {
            const uint4 u = *(const uint4*)&w2p[(i << 5) + (op << 2)];
            const int o = op << 3;
            const float w0 = BFLO(u.x), w1 = BFHI(u.x), w2 = BFLO(u.y), w3 = BFHI(u.y);
            const float w4 = BFLO(u.z), w5 = BFHI(u.z), w6 = BFLO(u.w), w7 = BFHI(u.w);
            h2a[o+0] += va*w0; h2b[o+0] += vb*w0;
            h2a[o+1] += va*w1; h2b[o+1] += vb*w1;
            h2a[o+2] += va*w2; h2b[o+2] += vb*w2;
            h2a[o+3] += va*w3; h2b[o+3] += vb*w3;
            h2a[o+4] += va*w4; h2b[o+4] += vb*w4;
            h2a[o+5] += va*w5; h2b[o+5] += vb*w5;
            h2a[o+6] += va*w6; h2b[o+6] += vb*w6;
            h2a[o+7] += va*w7; h2b[o+7] += vb*w7;
        }
    }
#pragma unroll
    for (int o = 0; o < 64; ++o) { h2a[o] = fmaxf(h2a[o], 0.f); h2b[o] = fmaxf(h2b[o], 0.f); }

    const float* __restrict__ xr0 = x + (size_t)((b << 12) | j0) * NC;
    const float* __restrict__ xr1 = x + (size_t)((b << 12) | j1) * NC;
    float* __restrict__ pout = pooled + (size_t)q * 64;

    for (int o = 0; o < 64; ++o) {
        float acca = b3s[o], accb = acca;
#pragma unroll
        for (int ip = 0; ip < 8; ++ip) {
            const uint4 u = *(const uint4*)&w3p[(o << 5) + (ip << 2)];
            const int i = ip << 3;
            const float w0 = BFLO(u.x), w1 = BFHI(u.x), w2 = BFLO(u.y), w3 = BFHI(u.y);
            const float w4 = BFLO(u.z), w5 = BFHI(u.z), w6 = BFLO(u.w), w7 = BFHI(u.w);
            acca += h2a[i+0]*w0 + h2a[i+1]*w1 + h2a[i+2]*w2 + h2a[i+3]*w3
                  + h2a[i+4]*w4 + h2a[i+5]*w5 + h2a[i+6]*w6 + h2a[i+7]*w7;
            accb += h2b[i+0]*w0 + h2b[i+1]*w1 + h2b[i+2]*w2 + h2b[i+3]*w3
                  + h2b[i+4]*w4 + h2b[i+5]*w5 + h2b[i+6]*w6 + h2b[i+7]*w7;
        }
        const float fa = (o < NC) ? xr0[o] : (o == 61 ? pa.x : (o == 62 ? pa.y : pa.z));
        const float fb = (o < NC) ? xr1[o] : (o == 61 ? pc.x : (o == 62 ? pc.y : pc.z));
        float f = fmaxf(fa * acca, fb * accb);
#pragma unroll
        for (int m = 1; m < 8; m <<= 1) f = fmaxf(f, __shfl_xor(f, m, 8));
        if (k8 == 0) pout[o] = fmaxf(f, 0.f);   // relu AFTER max-pool
    }
}

// ---------------------------------------------------------------------------
// Kernel 3: y1 = pooled(16384x64) @ fw1(64x128) + fb1 ; accumulate sum/sumsq.
// ---------------------------------------------------------------------------
__global__ __launch_bounds__(256) void gemm1_kernel(
    const float* __restrict__ A, const float* __restrict__ W,
    const float* __restrict__ bias, float* __restrict__ y,
    float* __restrict__ sum, float* __restrict__ sumsq) {
    __shared__ float As[64 * 64];
    __shared__ float Bs[64 * 128];
    const int t = threadIdx.x;
    const int r0 = blockIdx.x * 64;
    for (int i = t; i < 64 * 128; i += 256) Bs[i] = W[i];
    for (int i = t; i < 64 * 64; i += 256)  As[i] = A[(size_t)r0 * 64 + i];
    __syncthreads();

    const int c = t & 127, rg = t >> 7;
    float acc[32];
    const float bv = bias[c];
#pragma unroll
    for (int r = 0; r < 32; ++r) acc[r] = bv;

    for (int kk = 0; kk < 64; kk += 4) {
        const float b0 = Bs[(kk + 0) * 128 + c];
        const float b1 = Bs[(kk + 1) * 128 + c];
        const float b2 = Bs[(kk + 2) * 128 + c];
        const float b3 = Bs[(kk + 3) * 128 + c];
#pragma unroll
        for (int r = 0; r < 32; ++r) {
            const float4 a = *(const float4*)&As[(rg * 32 + r) * 64 + kk];
            acc[r] += a.x * b0 + a.y * b1 + a.z * b2 + a.w * b3;
        }
    }

    float s = 0.f, s2 = 0.f;
#pragma unroll
    for (int r = 0; r < 32; ++r) {
        const float v = acc[r];
        s += v; s2 += v * v;
        y[(size_t)(r0 + rg * 32 + r) * 128 + c] = v;
    }
    __syncthreads();
    As[t] = s; As[256 + t] = s2;
    __syncthreads();
    if (rg == 0) {
        atomicAdd(&sum[c],   As[c] + As[128 + c]);
        atomicAdd(&sumsq[c], As[256 + c] + As[256 + 128 + c]);
    }
}

// ---------------------------------------------------------------------------
// Kernel 4: h1 = relu(bn1(y1)); y2 = h1 @ fw2(128x128) + fb2 ; sum/sumsq.
// ---------------------------------------------------------------------------
__global__ __launch_bounds__(256) void gemm2_kernel(
    const float* __restrict__ y1, const float* __restrict__ W,
    const float* __restrict__ bias,
    const float* __restrict__ sum1, const float* __restrict__ sumsq1,
    const float* __restrict__ g1, const float* __restrict__ b1,
    float* __restrict__ y2, float* __restrict__ sum2, float* __restrict__ sumsq2) {
    __shared__ float As[64 * 128];
    __shared__ float Bs[64 * 128];
    __shared__ float a1s[128], s1s[128];
    const int t = threadIdx.x;
    const int r0 = blockIdx.x * 64;

    if (t < 128) {
        const float m = sum1[t] * INV_ROWS;
        const float v = sumsq1[t] * INV_ROWS - m * m;
        const float a = rsqrtf(v + BN_EPS) * g1[t];
        a1s[t] = a; s1s[t] = b1[t] - m * a;
    }
    for (int i = t; i < 64 * 128; i += 256) Bs[i] = W[i];   // fw2 rows 0..63
    __syncthreads();
    for (int i = t; i < 64 * 128; i += 256) {
        const int cc = i & 127;
        const float v = y1[(size_t)r0 * 128 + i];
        As[i] = fmaxf(v * a1s[cc] + s1s[cc], 0.f);
    }
    __syncthreads();

    const int c = t & 127, rg = t >> 7;
    float acc[32];
    const float bv = bias[c];
#pragma unroll
    for (int r = 0; r < 32; ++r) acc[r] = bv;

    for (int kk = 0; kk < 64; kk += 4) {
        const float b0 = Bs[(kk + 0) * 128 + c];
        const float b1v = Bs[(kk + 1) * 128 + c];
        const float b2 = Bs[(kk + 2) * 128 + c];
        const float b3 = Bs[(kk + 3) * 128 + c];
#pragma unroll
        for (int r = 0; r < 32; ++r) {
            const float4 a = *(const float4*)&As[(rg * 32 + r) * 128 + kk];
            acc[r] += a.x * b0 + a.y * b1v + a.z * b2 + a.w * b3;
        }
    }
    __syncthreads();
    for (int i = t; i < 64 * 128; i += 256) Bs[i] = W[64 * 128 + i];  // rows 64..127
    __syncthreads();
    for (int kk = 0; kk < 64; kk += 4) {
        const float b0 = Bs[(kk + 0) * 128 + c];
        const float b1v = Bs[(kk + 1) * 128 + c];
        const float b2 = Bs[(kk + 2) * 128 + c];
        const float b3 = Bs[(kk + 3) * 128 + c];
#pragma unroll
        for (int r = 0; r < 32; ++r) {
            const float4 a = *(const float4*)&As[(rg * 32 + r) * 128 + 64 + kk];
            acc[r] += a.x * b0 + a.y * b1v + a.z * b2 + a.w * b3;
        }
    }

    float s = 0.f, s2 = 0.f;
#pragma unroll
    for (int r = 0; r < 32; ++r) {
        const float v = acc[r];
        s += v; s2 += v * v;
        y2[(size_t)(r0 + rg * 32 + r) * 128 + c] = v;
    }
    __syncthreads();
    As[t] = s; As[256 + t] = s2;
    __syncthreads();
    if (rg == 0) {
        atomicAdd(&sum2[c],   As[c] + As[128 + c]);
        atomicAdd(&sumsq2[c], As[256 + c] + As[256 + 128 + c]);
    }
}

// ---------------------------------------------------------------------------
// Kernel 5: out = bn2(y2)  (no relu on the final stage)
// ---------------------------------------------------------------------------
__global__ __launch_bounds__(256) void bnout_kernel(
    const float* __restrict__ y2, const float* __restrict__ sum2,
    const float* __restrict__ sumsq2, const float* __restrict__ g2,
    const float* __restrict__ b2, float* __restrict__ out) {
    const int i = blockIdx.x * 256 + threadIdx.x;
    const int c = i & 127;
    const float m = sum2[c] * INV_ROWS;
    const float v = sumsq2[c] * INV_ROWS - m * m;
    const float a = rsqrtf(v + BN_EPS) * g2[c];
    out[i] = y2[i] * a + (b2[c] - m * a);
}

extern "C" void kernel_launch(void* const* d_in, const int* in_sizes, int n_in,
                              void* d_out, int out_size, void* d_ws, size_t ws_size,
                              hipStream_t stream) {
    const float* x   = (const float*)d_in[0];
    const float* pos = (const float*)d_in[1];
    const float* rw1 = (const float*)d_in[2];
    const float* rb1 = (const float*)d_in[3];
    const float* rw2 = (const float*)d_in[4];
    const float* rb2 = (const float*)d_in[5];
    const float* rw3 = (const float*)d_in[6];
    const float* rb3 = (const float*)d_in[7];
    const float* fw1 = (const float*)d_in[8];
    const float* fb1 = (const float*)d_in[9];
    const float* g1  = (const float*)d_in[10];
    const float* b1  = (const float*)d_in[11];
    const float* fw2 = (const float*)d_in[12];
    const float* fb2 = (const float*)d_in[13];
    const float* g2  = (const float*)d_in[14];
    const float* b2  = (const float*)d_in[15];
    float* out = (float*)d_out;

    char* ws = (char*)d_ws;
    int*    idx    = (int*)ws;                         // 16384*16 ints   (1 MB)
    float*  pooled = (float*)(ws + (1u << 20));        // 16384*64 f32    (4 MB)
    float*  y1     = (float*)(ws + (5u << 20));        // 16384*128 f32   (8 MB)
    float*  y2     = (float*)(ws + (13u << 20));       // 16384*128 f32   (8 MB)
    float*  stats  = (float*)(ws + (21u << 20));       // 4*128 f32
    float4* pos4   = (float4*)(ws + (22u << 20));      // 16384 float4    (256 KB)
    float* sum1 = stats, *sumsq1 = stats + 128, *sum2 = stats + 256, *sumsq2 = stats + 384;

    hipMemsetAsync(stats, 0, 512 * sizeof(float), stream);

    prep_pos4<<<64, 256, 0, stream>>>(pos, pos4);
    knn_kernel<<<2048, 256, 0, stream>>>(pos4, idx);
    mlp_kernel<<<512, 256, 0, stream>>>(pos4, x, idx, rw1, rb1, rw2, rb2, rw3, rb3, pooled);
    gemm1_kernel<<<256, 256, 0, stream>>>(pooled, fw1, fb1, y1, sum1, sumsq1);
    gemm2_kernel<<<256, 256, 0, stream>>>(y1, fw2, fb2, sum1, sumsq1, g1, b1, y2, sum2, sumsq2);
    bnout_kernel<<<NROWS * 128 / 256, 256, 0, stream>>>(y2, sum2, sumsq2, g2, b2, out);
}